// Round 4
// baseline (400.399 us; speedup 1.0000x reference)
//
#include <hip/hip_runtime.h>
#include <hip/hip_bf16.h>
#include <stdint.h>

#define ENC_DIM 2048
#define DEC_DIM 512
#define ATT_DIM 512
#define BATCH   256
#define PIX     196
#define M_TOTAL (BATCH*PIX)   // 50176
#define NT      (ENC_DIM/64)  // 32 K-tiles

typedef unsigned short u16;
typedef __attribute__((ext_vector_type(8))) short  bf16x8;
typedef __attribute__((ext_vector_type(4))) float  f32x4;

// ---------- helpers ----------
__device__ __forceinline__ void gll16(const void* g, void* l) {
    __builtin_amdgcn_global_load_lds(
        (const __attribute__((address_space(1))) unsigned int*)g,
        (__attribute__((address_space(3))) unsigned int*)l,
        16, 0, 0);
}

union Pack8 {
    uint4 u;
    __hip_bfloat16 h[8];
};

__device__ __forceinline__ uint4 cvt8(float4 a, float4 b) {
    Pack8 p;
    p.h[0] = __float2bfloat16(a.x); p.h[1] = __float2bfloat16(a.y);
    p.h[2] = __float2bfloat16(a.z); p.h[3] = __float2bfloat16(a.w);
    p.h[4] = __float2bfloat16(b.x); p.h[5] = __float2bfloat16(b.y);
    p.h[6] = __float2bfloat16(b.z); p.h[7] = __float2bfloat16(b.w);
    return p.u;
}

// ---------- kernel 1: W_enc fp32 -> bf16 ----------
__global__ void k_convert(const float* __restrict__ W, u16* __restrict__ Wb) {
    int idx = blockIdx.x * 256 + threadIdx.x;
    const float4* s = (const float4*)W + (size_t)idx * 2;
    ((uint4*)Wb)[idx] = cvt8(s[0], s[1]);
}

// ---------- kernel 2: att2[b,a] = dec[b,:].W_dec[a,:] + b_enc[a] + b_dec[a] ----------
__global__ void k_att2(const float* __restrict__ dec, const float* __restrict__ Wd,
                       const float* __restrict__ b_enc, const float* __restrict__ b_dec,
                       float* __restrict__ att2f) {
    int b = blockIdx.x;
    int t = threadIdx.x;
    __shared__ float dec_s[DEC_DIM];
    ((float2*)dec_s)[t] = ((const float2*)(dec + (size_t)b * DEC_DIM))[t];
    __syncthreads();
    #pragma unroll
    for (int rep = 0; rep < 2; ++rep) {
        int a = t + rep * 256;
        const float4* w = (const float4*)(Wd + (size_t)a * DEC_DIM);
        float acc = 0.f;
        #pragma unroll 4
        for (int e = 0; e < DEC_DIM / 4; ++e) {
            float4 wv = w[e];
            float4 dv = ((const float4*)dec_s)[e];
            acc += wv.x * dv.x + wv.y * dv.y + wv.z * dv.z + wv.w * dv.w;
        }
        att2f[(size_t)b * ATT_DIM + a] = acc + b_enc[a] + b_dec[a];
    }
}

// ---------- kernel 3: 8-phase-style fused GEMM ----------
// BM=256 BN=128 BK=64, 8 waves (4Mx2N), per-wave 64x64, dbuf LDS (96KB).
// Per K-tile: 2 phases {8 ds_read | stage-issue | SBAR | lgkm0 | 16 MFMA | SBAR},
// counted vmcnt: gate(10) for A-regs, trailing(8) keeps next A-loads in flight.

#define FENCE  asm volatile("" ::: "memory")
#define LGKM0  asm volatile("s_waitcnt lgkmcnt(0)" ::: "memory")
#define VMC(N) asm volatile("s_waitcnt vmcnt(" #N ")" ::: "memory")
#define SBARF  do { FENCE; __builtin_amdgcn_s_barrier(); FENCE; } while (0)

// 8 global fp32x4 loads for A-tile KT (coalesced 256B groups)
#define ISSUE_A(KT, F) do { const float* _p = a_src + (size_t)(KT) * 64;               \
    _Pragma("unroll") for (int s = 0; s < 4; ++s) {                                    \
        F[2*s]   = *(const float4*)(_p + (size_t)s * 64 * ENC_DIM);                    \
        F[2*s+1] = *(const float4*)(_p + (size_t)s * 64 * ENC_DIM + 4); } } while (0)

// cvt + 4 swizzled ds_write_b128 into As[Q]
#define WRITE_A(Q, F) do { _Pragma("unroll") for (int s = 0; s < 4; ++s)               \
    *(uint4*)(&As[Q][aw_off + s * 4096]) = cvt8(F[2*s], F[2*s+1]); } while (0)

// 2 gll16 staging B-tile KT into Bs[Q] (pre-swizzled source, linear dest)
#define STAGE_B(KT, Q) do {                                                            \
    gll16(b_src0 + (size_t)(KT) * 64, &Bs[Q][b_dst0]);                                 \
    gll16(b_src1 + (size_t)(KT) * 64, &Bs[Q][b_dst1]); } while (0)

#define RD_FRAGS(P, AXO) do {                                                          \
    _Pragma("unroll") for (int m = 0; m < 4; ++m)                                      \
        af[m] = *(const bf16x8*)(&As[P][a_row_off + m * 1024 + (AXO)]);                \
    _Pragma("unroll") for (int n = 0; n < 4; ++n)                                      \
        bf[n] = *(const bf16x8*)(&Bs[P][b_row_off + n * 1024 + (AXO)]); } while (0)

#define MMA16 do { __builtin_amdgcn_s_setprio(1);                                      \
    _Pragma("unroll") for (int m = 0; m < 4; ++m)                                      \
        _Pragma("unroll") for (int n = 0; n < 4; ++n)                                  \
            acc[m][n] = __builtin_amdgcn_mfma_f32_16x16x32_bf16(af[m], bf[n], acc[m][n], 0, 0, 0); \
    __builtin_amdgcn_s_setprio(0); } while (0)

// main-loop tile: stages B(KT+1)->Q, issues A(KT+2)->FWR, writes A(KT+1)=FUSE->Q
#define TILE_MAIN(KT, P, Q, FWR, FUSE) do {                                            \
    bf16x8 af[4], bf[4];                                                               \
    RD_FRAGS(P, axo0);                                                                 \
    STAGE_B((KT) + 1, Q); FENCE;                                                       \
    ISSUE_A((KT) + 2, FWR);                                                            \
    SBARF; LGKM0; MMA16; SBARF;                                                        \
    RD_FRAGS(P, axo1);                                                                 \
    VMC(10);            /* newer than A(KT+1): g(KT+1)x2 + A(KT+2)x8 */                \
    WRITE_A(Q, FUSE);                                                                  \
    SBARF; LGKM0; MMA16;                                                               \
    VMC(8);             /* drain g(KT+1); A(KT+2)x8 stay in flight */                  \
    SBARF; } while (0)

__global__ void __launch_bounds__(512, 2)
k_gemm(const float* __restrict__ enc, const u16* __restrict__ Wb,
       const float* __restrict__ att2f, const float* __restrict__ Wfull,
       float* __restrict__ att_part) {
    const int bid = blockIdx.x;
    const int wg  = (bid & 7) * 98 + (bid >> 3);   // 784 = 8*98, bijective XCD chunking
    const int mb  = wg >> 2, nb = wg & 3;          // 4 nb-blocks share the A panel
    const int t   = threadIdx.x;
    const int lane = t & 63, wave = t >> 6;
    const int wm = wave >> 1, wn = wave & 1;       // 4M x 2N wave grid
    const int fr = lane & 15, fq = lane >> 4;

    __shared__ u16 As[2][256 * 64];  // 2 x 32 KB
    __shared__ u16 Bs[2][128 * 64];  // 2 x 16 KB

    f32x4 acc[4][4];
    #pragma unroll
    for (int m = 0; m < 4; ++m)
        #pragma unroll
        for (int n = 0; n < 4; ++n)
            acc[m][n] = (f32x4){0.f, 0.f, 0.f, 0.f};

    // A staging: thread t covers rows s*64 + (t>>3), k-octet t&7; write-side swizzle
    const int arow  = t >> 3;
    const int aslot = t & 7;
    const float* a_src = enc + (size_t)(mb * 256 + arow) * ENC_DIM + aslot * 8;
    const int aw_off = arow * 64 + ((aslot ^ (arow & 7))) * 8;

    // B staging via gll16: lane covers row sweep + (lane>>3), slot lane&7;
    // source octet pre-swizzled (rule #21), dest linear
    const int brl = lane >> 3, bslot = lane & 7;
    const u16* b_src0 = Wb + (size_t)(nb * 128 + wave * 8 + brl) * ENC_DIM + (bslot ^ brl) * 8;
    const u16* b_src1 = b_src0 + (size_t)64 * ENC_DIM;
    const int b_dst0 = (wave * 8) * 64;
    const int b_dst1 = (64 + wave * 8) * 64;

    // fragment reads: row = w*64 + m*16 + fr, slot = ((ks<<2)|fq) ^ (fr&7)
    const int r7 = fr & 7;
    const int axo0 = ((fq    ) ^ r7) * 8;
    const int axo1 = ((fq | 4) ^ r7) * 8;
    const int a_row_off = (wm * 64 + fr) * 64;
    const int b_row_off = (wn * 64 + fr) * 64;

    float4 fE[8], fO[8];   // 2-deep A-reg pipeline, parity-named (rule #20)

    // ---- prologue: stage tile 0, issue A(1) ----
    ISSUE_A(0, fE); FENCE;
    STAGE_B(0, 0);
    VMC(2);                // A(0) regs ready (g(0)x2 newer)
    WRITE_A(0, fE);
    FENCE; ISSUE_A(1, fO);
    VMC(8); LGKM0;         // g(0) drained; A-writes done; A(1)x8 in flight
    SBARF;

    // ---- main loop: tiles 0..29, 2 per iteration ----
    for (int tt = 0; tt < NT - 2; tt += 2) {
        TILE_MAIN(tt,     0, 1, fE, fO);   // even tile: buf0, stage->buf1
        TILE_MAIN(tt + 1, 1, 0, fO, fE);   // odd tile:  buf1, stage->buf0
    }

    // ---- tile 30 (P=0, Q=1): stage B(31)+A(31), no A(32) ----
    {
        bf16x8 af[4], bf[4];
        RD_FRAGS(0, axo0);
        STAGE_B(31, 1); FENCE;
        SBARF; LGKM0; MMA16; SBARF;
        RD_FRAGS(0, axo1);
        VMC(2);            // A(31) regs ready (g(31)x2 newer)
        WRITE_A(1, fO);
        SBARF; LGKM0; MMA16;
        VMC(0);            // drain g(31)
        SBARF;
    }
    // ---- tile 31 (P=1): pure compute ----
    {
        bf16x8 af[4], bf[4];
        RD_FRAGS(1, axo0);
        LGKM0; MMA16;
        RD_FRAGS(1, axo1);
        LGKM0; MMA16;
    }

    // ---- epilogue: +att2, relu, dot W_full, 16-lane reduce ----
    // C/D layout: col = lane&15, row = (lane>>4)*4 + reg  [m89/m91]
    const int row_base = mb * 256 + wm * 64 + fq * 4;
    const int col_base = nb * 128 + wn * 64 + fr;
    float wf[4];
    #pragma unroll
    for (int n = 0; n < 4; ++n) wf[n] = Wfull[col_base + n * 16];

    #pragma unroll
    for (int m = 0; m < 4; ++m) {
        #pragma unroll
        for (int r = 0; r < 4; ++r) {
            const int grow = row_base + m * 16 + r;
            const int bidx = grow / PIX;
            const float* a2 = att2f + (size_t)bidx * ATT_DIM;
            float ssum = 0.f;
            #pragma unroll
            for (int n = 0; n < 4; ++n) {
                float v = acc[m][n][r] + a2[col_base + n * 16];
                v = fmaxf(v, 0.f);
                ssum += v * wf[n];
            }
            #pragma unroll
            for (int off = 1; off < 16; off <<= 1)
                ssum += __shfl_xor(ssum, off, 64);
            if (fr == 0)
                att_part[(size_t)(nb * 2 + wn) * M_TOTAL + grow] = ssum;
        }
    }
}

// ---------- kernel 4: per-b softmax over 196 + alpha-weighted enc reduction ----------
__global__ void k_soft(const float* __restrict__ att_part, const float* __restrict__ enc,
                       float* __restrict__ out) {
    const int b  = blockIdx.x >> 1;
    const int ec = blockIdx.x & 1;   // e-chunk of 1024
    const int t  = threadIdx.x;
    __shared__ float red[256];
    __shared__ float alpha_s[PIX];

    float myatt = -1e30f;
    if (t < PIX) {
        float s = 0.f;
        #pragma unroll
        for (int j = 0; j < 8; ++j) s += att_part[(size_t)j * M_TOTAL + b * PIX + t];
        myatt = s;
    }
    red[t] = myatt;
    __syncthreads();
    for (int o = 128; o > 0; o >>= 1) {
        if (t < o) red[t] = fmaxf(red[t], red[t + o]);
        __syncthreads();
    }
    const float mx = red[0];
    __syncthreads();
    float e = 0.f;
    if (t < PIX) e = __expf(myatt - mx);
    red[t] = e;
    __syncthreads();
    for (int o = 128; o > 0; o >>= 1) {
        if (t < o) red[t] += red[t + o];
        __syncthreads();
    }
    const float inv = 1.f / red[0];
    if (t < PIX) {
        float al = e * inv;
        alpha_s[t] = al;
        if (ec == 0) out[(size_t)BATCH * ENC_DIM + b * PIX + t] = al;   // alpha output
    }
    __syncthreads();

    float4 acc = {0.f, 0.f, 0.f, 0.f};
    const float* ebase = enc + (size_t)b * PIX * ENC_DIM + ec * 1024 + t * 4;
    #pragma unroll 4
    for (int p = 0; p < PIX; ++p) {
        float4 x = *(const float4*)(ebase + (size_t)p * ENC_DIM);
        float a = alpha_s[p];
        acc.x += a * x.x; acc.y += a * x.y; acc.z += a * x.z; acc.w += a * x.w;
    }
    *(float4*)(out + (size_t)b * ENC_DIM + ec * 1024 + t * 4) = acc;
}

extern "C" void kernel_launch(void* const* d_in, const int* in_sizes, int n_in,
                              void* d_out, int out_size, void* d_ws, size_t ws_size,
                              hipStream_t stream) {
    const float* enc    = (const float*)d_in[0];
    const float* dec    = (const float*)d_in[1];
    const float* W_enc  = (const float*)d_in[2];
    const float* b_enc  = (const float*)d_in[3];
    const float* W_dec  = (const float*)d_in[4];
    const float* b_dec  = (const float*)d_in[5];
    const float* W_full = (const float*)d_in[6];
    // d_in[7] (b_full) unused: softmax is shift-invariant, att is not an output.

    char* ws = (char*)d_ws;
    u16*   Wb    = (u16*)ws;                                    // 2 MB bf16 W_enc
    float* att2f = (float*)(ws + 2 * 1024 * 1024);              // 512 KB
    float* att_p = (float*)(ws + 2 * 1024 * 1024 + 512 * 1024); // 8 * 50176 * 4 B

    hipLaunchKernelGGL(k_convert, dim3(512), dim3(256), 0, stream, W_enc, Wb);
    hipLaunchKernelGGL(k_att2,    dim3(256), dim3(256), 0, stream, dec, W_dec, b_enc, b_dec, att2f);
    hipLaunchKernelGGL(k_gemm,    dim3(784), dim3(512), 0, stream, enc, Wb, att2f, W_full, att_p);
    hipLaunchKernelGGL(k_soft,    dim3(512), dim3(256), 0, stream, att_p, enc, (float*)d_out);
}